// Round 5
// baseline (184.419 us; speedup 1.0000x reference)
//
#include <hip/hip_runtime.h>

#define CELLS 81
#define ND 9
#define HID 100
#define NU 7   // hidden units per lane: u = (l&15) + 16k, k < 7

__global__ __launch_bounds__(64) void sudoku_kernel(
    const float* __restrict__ x_all,
    const float* __restrict__ W1,
    const float* __restrict__ W2,
    float* __restrict__ out,
    int nBoards)
{
    const int board = blockIdx.x;
    const int l = threadIdx.x;          // 0..63, one wave: lockstep, no barriers
    const int s = l & 15;               // sub-lane within 16-lane cell group
    const int grp = l >> 4;             // which of 4 cells this lane serves
    const float* x = x_all + (size_t)board * (CELLS * ND);
    float* po = out + (size_t)board * (CELLS * ND);
    float* fo = out + (size_t)nBoards * (CELLS * ND) + (size_t)board * (CELLS * ND);

    __shared__ float z[CELLS * HID];     // 32400 B pre-activations
    __shared__ float smax[CELLS * ND];   // 2916 B cached softmax per cell
    __shared__ float cnt[3 * 81];        // 972 B (init only)
    __shared__ int   digit[CELLS];
    __shared__ int   lst[CELLS];         // compacted empty list
    __shared__ float scoreV[CELLS];
    __shared__ int   scoreD[CELLS];
    __shared__ int   chlist[CELLS];      // q | mask<<8

    // ---- W2 column slices in registers ----
    float w2r[NU][ND];
    #pragma unroll
    for (int k = 0; k < NU; ++k) {
        int u = s + 16 * k;
        #pragma unroll
        for (int d = 0; d < ND; ++d)
            w2r[k][d] = (u < HID) ? W2[d * HID + u] : 0.f;
    }

    // ---- init ----
    for (int i = l; i < 243; i += 64) cnt[i] = 0.f;
    for (int i = l; i < CELLS * ND; i += 64) po[i] = x[i];

    int ne = 0;
    #pragma unroll
    for (int pass = 0; pass < 2; ++pass) {
        int q = pass * 64 + l;
        bool valid = q < CELLS;
        int dig = -1;
        if (valid) {
            #pragma unroll
            for (int d = 0; d < ND; ++d)
                if (dig < 0 && x[q * ND + d] > 0.5f) dig = d;
            digit[q] = dig;
            if (dig >= 0) {
                int r = q / 9, c = q - r * 9, bx = (r / 3) * 3 + c / 3;
                atomicAdd(&cnt[r * 9 + dig], 1.f);
                atomicAdd(&cnt[81 + c * 9 + dig], 1.f);
                atomicAdd(&cnt[162 + bx * 9 + dig], 1.f);
            }
        }
        unsigned long long mk = __ballot(valid && dig < 0);
        if (valid && dig < 0) {
            int pos = ne + __popcll(mk & ((1ull << l) - 1ull));
            lst[pos] = q;
        }
        ne += __popcll(mk);
    }

    // ---- z init for empty cells ----
    for (int i = l; i < ne * HID; i += 64) {
        int qi = i / HID, u = i - qi * HID;
        int q = lst[qi];
        int r = q / 9, c = q - r * 9, bx = (r / 3) * 3 + c / 3;
        const float* w = &W1[u * 27];
        float a0 = 0.f, a1 = 0.f, a2 = 0.f;
        #pragma unroll
        for (int j = 0; j < 9; ++j) {
            a0 += cnt[r * 9 + j] * w[j];
            a1 += cnt[81 + c * 9 + j] * w[9 + j];
            a2 += cnt[162 + bx * 9 + j] * w[18 + j];
        }
        z[q * HID + u] = a0 + a1 + a2;
    }

    // ---- solve loop: zero barriers, wave-synchronous ----
    int pC = -1, dC = 0;
    float w1d0[NU], w1d9[NU], w1d18[NU];
    while (ne > 0) {
        int nch;
        if (pC < 0) {
            for (int i = l; i < ne; i += 64) chlist[i] = lst[i];  // mask = 0
            nch = ne;
        } else {
            // prefetch W1 delta column for this placement's digit
            #pragma unroll
            for (int k = 0; k < NU; ++k) {
                int u = s + 16 * k;
                if (u < HID) {
                    const float* wp = &W1[u * 27 + dC];
                    w1d0[k] = wp[0]; w1d9[k] = wp[9]; w1d18[k] = wp[18];
                } else { w1d0[k] = w1d9[k] = w1d18[k] = 0.f; }
            }
            int pr = pC / 9, pcc = pC - pr * 9, pb = (pr / 3) * 3 + pcc / 3;
            nch = 0;
            for (int base = 0; base < ne; base += 64) {
                int i = base + l;
                bool act = i < ne;
                int q = act ? lst[i] : 0;
                int m = 0;
                if (act) {
                    int r = q / 9, c = q - r * 9, bx = (r / 3) * 3 + c / 3;
                    m = (r == pr ? 1 : 0) | (c == pcc ? 2 : 0) | (bx == pb ? 4 : 0);
                }
                unsigned long long mk = __ballot(m != 0);
                if (m) {
                    int pos = nch + __popcll(mk & ((1ull << l) - 1ull));
                    chlist[pos] = q | (m << 8);
                }
                nch += __popcll(mk);
            }
        }

        // B/C: 4 cells per pass, 16 lanes each; fused z-delta + logits +
        // softmax + per-cell argmax (all lanes end with all 9 values).
        // Inactive groups MUST get mask=0 (e=0): an unguarded z write would
        // re-apply the delta to chlist[0]'s cell (round-4 bug).
        for (int p = 0; p * 4 < nch; ++p) {
            int ci = p * 4 + grp;
            bool act = ci < nch;
            int e = act ? chlist[ci] : 0;
            int q = e & 255, m = e >> 8;
            float acc[ND] = {0.f,0.f,0.f,0.f,0.f,0.f,0.f,0.f,0.f};
            #pragma unroll
            for (int k = 0; k < NU; ++k) {
                int u = s + 16 * k;
                if (u < HID) {
                    int idx = q * HID + u;
                    float zv = z[idx];
                    if (m) {
                        float dz = 0.f;
                        if (m & 1) dz += w1d0[k];
                        if (m & 2) dz += w1d9[k];
                        if (m & 4) dz += w1d18[k];
                        zv += dz;
                        z[idx] = zv;
                    }
                    float h = fmaxf(zv, 0.f);
                    #pragma unroll
                    for (int d = 0; d < ND; ++d) acc[d] += h * w2r[k][d];
                }
            }
            #pragma unroll
            for (int off = 8; off >= 1; off >>= 1) {
                #pragma unroll
                for (int d = 0; d < ND; ++d)
                    acc[d] += __shfl_xor(acc[d], off, 16);
            }
            float m9 = acc[0];
            #pragma unroll
            for (int d = 1; d < ND; ++d) m9 = fmaxf(m9, acc[d]);
            float ssum = 0.f;
            #pragma unroll
            for (int d = 0; d < ND; ++d) { acc[d] = expf(acc[d] - m9); ssum += acc[d]; }
            float inv = 1.f / ssum;
            float bv = -1.f; int bd = 0;
            #pragma unroll
            for (int d = 0; d < ND; ++d) {
                acc[d] *= inv;
                if (acc[d] > bv) { bv = acc[d]; bd = d; }  // strict >: first max
            }
            if (act) {
                #pragma unroll
                for (int d = 0; d < ND; ++d)
                    if (s == d) smax[q * ND + d] = acc[d];
                if (s == 0) { scoreV[q] = bv; scoreD[q] = bd; }
            }
        }

        // D: global argmax over empty cells (ties -> smallest q); every lane
        // ends with the winner, no broadcast needed
        float v = -1.f; int qb = 1 << 20, db = 0;
        for (int i = l; i < ne; i += 64) {
            int q = lst[i];
            float sv = scoreV[q];
            if (sv > v || (sv == v && q < qb)) { v = sv; qb = q; db = scoreD[q]; }
        }
        #pragma unroll
        for (int off = 32; off >= 1; off >>= 1) {
            float ov = __shfl_xor(v, off);
            int   oq = __shfl_xor(qb, off);
            int   od = __shfl_xor(db, off);
            if (ov > v || (ov == v && oq < qb)) { v = ov; qb = oq; db = od; }
        }

        // place: write po for the filled cell (its last softmax), update state
        if (l == 0) digit[qb] = db;
        if (l < ND) po[qb * ND + l] = smax[qb * ND + l];
        int pos = 0;
        for (int base = 0; base < ne; base += 64) {
            int i = base + l;
            unsigned long long mk = __ballot(i < ne && lst[i] == qb);
            if (mk) pos = base + (__ffsll((unsigned long long)mk) - 1);
        }
        if (l == 0) lst[pos] = lst[ne - 1];
        ne--; pC = qb; dC = db;
    }

    // ---- x_final ----
    for (int i = l; i < CELLS * ND; i += 64) {
        int q = i / ND, d = i - q * ND;
        fo[i] = (digit[q] == d) ? 1.0f : 0.0f;
    }
}

extern "C" void kernel_launch(void* const* d_in, const int* in_sizes, int n_in,
                              void* d_out, int out_size, void* d_ws, size_t ws_size,
                              hipStream_t stream) {
    const float* x  = (const float*)d_in[0];
    // d_in[1] is the constraint mask c — structurally known, not needed.
    const float* W1 = (const float*)d_in[2];
    const float* W2 = (const float*)d_in[3];
    float* out = (float*)d_out;
    int nBoards = in_sizes[0] / (CELLS * ND);
    sudoku_kernel<<<nBoards, 64, 0, stream>>>(x, W1, W2, out, nBoards);
}